// Round 1
// baseline (490.470 us; speedup 1.0000x reference)
//
#include <hip/hip_runtime.h>

#define HH 256
#define WW 256
#define BATCH 8
#define CH 64
#define NIMG (BATCH*CH)      // 512
#define HWSZ (HH*WW)         // 65536
#define ROWS 8
#define STRIPS (HH/ROWS)     // 32
#define SCL (1.0f/12.0f)
#define KHARRIS 0.04f
#define TFRAC 0.7f

__device__ __forceinline__ int refl(int i, int n) {
    return i < 0 ? -i : (i >= n ? 2*n - 2 - i : i);
}
// order-preserving float->uint encoding for atomicMax
__device__ __forceinline__ unsigned encf(float f) {
    unsigned u = __float_as_uint(f);
    return (u & 0x80000000u) ? ~u : (u | 0x80000000u);
}
__device__ __forceinline__ float decf(unsigned u) {
    return __uint_as_float((u & 0x80000000u) ? (u & 0x7fffffffu) : ~u);
}

__global__ void init_kernel(unsigned* maxslot) {
    int i = blockIdx.x * blockDim.x + threadIdx.x;
    if (i < NIMG) maxslot[i] = 0u;   // below enc of any real float
}

// One block = one image strip of ROWS rows x 256 cols. Thread = column.
// Separable stages; LDS only for horizontal neighbor exchange.
template<bool WRITE_ATT>
__global__ __launch_bounds__(256) void harris_kernel(const float* __restrict__ x,
                                                     unsigned* __restrict__ maxslot,
                                                     unsigned char* __restrict__ att)
{
    __shared__ float lds[3*(ROWS+2)*256];   // 30 rows x 256 = 30720 B (unioned across stages)
    const int tid = threadIdx.x;
    const int img = blockIdx.x / STRIPS;
    const int strip = blockIdx.x % STRIPS;
    const int r0 = strip * ROWS;
    const float* ib = x + (size_t)img * HWSZ;

    // ---- load img rows r0-3 .. r0+ROWS+2 (reflect101 at image border) ----
    float iv[ROWS+6];
#pragma unroll
    for (int i = 0; i < ROWS+6; ++i) {
        int gr = refl(r0 - 3 + i, HH);
        iv[i] = ib[gr * WW + tid];
    }

    // ---- vertical parts of Sobel for rows r0-2+j, j=0..ROWS+3 ----
    // t1 = [1,2,1]v (for dx), t2 = [-1,0,1]v (for dy)
#pragma unroll
    for (int j = 0; j < ROWS+4; ++j) {
        lds[j*256 + tid]          = iv[j] + 2.0f*iv[j+1] + iv[j+2];
        lds[(ROWS+4+j)*256 + tid] = iv[j+2] - iv[j];
    }
    __syncthreads();

    const int cm = (tid == 0)    ? 1      : tid - 1;   // reflect101 columns (conv stages)
    const int cp = (tid == WW-1) ? WW - 2 : tid + 1;

    float dxv[ROWS+4], dyv[ROWS+4];
#pragma unroll
    for (int j = 0; j < ROWS+4; ++j) {
        dxv[j] = SCL * (lds[j*256 + cp] - lds[j*256 + cm]);
        dyv[j] = SCL * (lds[(ROWS+4+j)*256 + cm] + 2.0f*lds[(ROWS+4+j)*256 + tid]
                        + lds[(ROWS+4+j)*256 + cp]);
    }
    __syncthreads();   // all t1/t2 reads done before LDS reuse

    // ---- products + vertical box sums S for rows gr=r0-1+k, k=0..ROWS+1 ----
    // S row k uses product rows gr-1..gr+1 -> dx idx k,k+1,k+2 (interior)
#pragma unroll
    for (int k = 0; k < ROWS+2; ++k) {
        float a0 = dxv[k], a1 = dxv[k+1], a2 = dxv[k+2];
        float b0 = dyv[k], b1 = dyv[k+1], b2 = dyv[k+2];
        lds[k*256 + tid]              = a0*a0 + a1*a1 + a2*a2;  // Sxx
        lds[(ROWS+2+k)*256 + tid]     = a0*b0 + a1*b1 + a2*b2;  // Sxy
        lds[(2*(ROWS+2)+k)*256 + tid] = b0*b0 + b1*b1 + b2*b2;  // Syy
    }
    // Edge patches: the product FIELD is reflected (not recomputed on reflected img).
    if (r0 == 0) {
        // k=1 (gr=0): product rows -1,0,1 -> reflect -> 1,0,1 -> dx idx 3,2,3
        float a0 = dxv[3], a1 = dxv[2], a2 = dxv[3];
        float b0 = dyv[3], b1 = dyv[2], b2 = dyv[3];
        lds[1*256 + tid]              = a0*a0 + a1*a1 + a2*a2;
        lds[(ROWS+2+1)*256 + tid]     = a0*b0 + a1*b1 + a2*b2;
        lds[(2*(ROWS+2)+1)*256 + tid] = b0*b0 + b1*b1 + b2*b2;
    }
    if (r0 == HH-ROWS) {
        // k=ROWS (gr=255): product rows 254,255,256 -> reflect -> 254,255,254 -> idx 8,9,8
        float a0 = dxv[ROWS], a1 = dxv[ROWS+1], a2 = dxv[ROWS];
        float b0 = dyv[ROWS], b1 = dyv[ROWS+1], b2 = dyv[ROWS];
        lds[ROWS*256 + tid]              = a0*a0 + a1*a1 + a2*a2;
        lds[(ROWS+2+ROWS)*256 + tid]     = a0*b0 + a1*b1 + a2*b2;
        lds[(2*(ROWS+2)+ROWS)*256 + tid] = b0*b0 + b1*b1 + b2*b2;
    }
    __syncthreads();

    // ---- horizontal box + Harris R for rows gr=r0-1+k ----
    float Rv[ROWS+2];
#pragma unroll
    for (int k = 0; k < ROWS+2; ++k) {
        float ixx = lds[k*256 + cm] + lds[k*256 + tid] + lds[k*256 + cp];
        float ixy = lds[(ROWS+2+k)*256 + cm] + lds[(ROWS+2+k)*256 + tid] + lds[(ROWS+2+k)*256 + cp];
        float iyy = lds[(2*(ROWS+2)+k)*256 + cm] + lds[(2*(ROWS+2)+k)*256 + tid] + lds[(2*(ROWS+2)+k)*256 + cp];
        float tr = ixx + iyy;
        Rv[k] = (ixx*iyy - ixy*ixy) - KHARRIS*tr*tr;
    }

    if (!WRITE_ATT) {
        // per-image max of R over in-image rows r0..r0+ROWS-1 (k=1..ROWS)
        float m = Rv[1];
#pragma unroll
        for (int k = 2; k <= ROWS; ++k) m = fmaxf(m, Rv[k]);
#pragma unroll
        for (int off = 32; off > 0; off >>= 1) m = fmaxf(m, __shfl_xor(m, off));
        __syncthreads();
        if ((tid & 63) == 0) lds[tid >> 6] = m;
        __syncthreads();
        if (tid == 0) {
            float mm = fmaxf(fmaxf(lds[0], lds[1]), fmaxf(lds[2], lds[3]));
            atomicMax(maxslot + img, encf(mm));
        }
        return;
    }

    // ---- dilate: border rows/cols are -inf (NOT reflect) ----
    if (r0 == 0)        Rv[0]      = -__builtin_inff();   // gr=-1
    if (r0 == HH-ROWS)  Rv[ROWS+1] = -__builtin_inff();   // gr=256
    __syncthreads();   // done reading S arrays
#pragma unroll
    for (int m2 = 0; m2 < ROWS; ++m2) {
        lds[m2*256 + tid] = fmaxf(fmaxf(Rv[m2], Rv[m2+1]), Rv[m2+2]);  // vertical max
    }
    __syncthreads();

    const float t = TFRAC * decf(maxslot[img]);
    unsigned char* ab = att + (size_t)img * HWSZ;
#pragma unroll
    for (int m2 = 0; m2 < ROWS; ++m2) {
        float ctr = lds[m2*256 + tid];
        float lft = (tid == 0)    ? -__builtin_inff() : lds[m2*256 + tid - 1];
        float rgt = (tid == WW-1) ? -__builtin_inff() : lds[m2*256 + tid + 1];
        float dst = fmaxf(fmaxf(lft, ctr), rgt);
        unsigned char a = (dst > t) ? (unsigned char)1
                        : ((dst < t) ? (unsigned char)0 : (unsigned char)2);
        ab[(r0 + m2)*WW + tid] = a;
    }
}

// One block = one (b,h) row across all 64 channels. Thread = w.
// x column (64 ci) in VGPRs; weights are wave-uniform -> scalar loads.
__global__ __launch_bounds__(256) void conv_kernel(const float* __restrict__ x,
                                                   const float* __restrict__ wgt,
                                                   const float* __restrict__ bias,
                                                   const unsigned char* __restrict__ att,
                                                   float* __restrict__ out)
{
    const int tid = threadIdx.x;
    const int b = blockIdx.x >> 8;
    const int h = blockIdx.x & 255;
    const size_t base = (size_t)b * CH * HWSZ + (size_t)h * WW + tid;

    float xv[CH];
#pragma unroll
    for (int ci = 0; ci < CH; ++ci) xv[ci] = x[base + (size_t)ci * HWSZ];

    for (int c = 0; c < CH; ++c) {
        float acc = bias[c];
        const float* wr = wgt + c * CH;
#pragma unroll
        for (int ci = 0; ci < CH; ++ci) acc = fmaf(wr[ci], xv[ci], acc);
        float y = fmaxf(acc, 0.0f);
        size_t oidx = base + (size_t)c * HWSZ;         // == (b*CH+c)*HWSZ + h*WW + tid
        unsigned char a = att[oidx];
        float av = (a == 1) ? 1.0f : ((a == 0) ? 0.0f : xv[c]);
        out[oidx] = fmaf(av, y, xv[c]);
    }
}

extern "C" void kernel_launch(void* const* d_in, const int* in_sizes, int n_in,
                              void* d_out, int out_size, void* d_ws, size_t ws_size,
                              hipStream_t stream)
{
    const float* x    = (const float*)d_in[0];
    const float* wgt  = (const float*)d_in[1];
    const float* bias = (const float*)d_in[2];
    float* out = (float*)d_out;

    unsigned* maxslot = (unsigned*)d_ws;
    unsigned char* att = (unsigned char*)d_ws + 4096;

    hipLaunchKernelGGL(init_kernel, dim3(2), dim3(256), 0, stream, maxslot);
    hipLaunchKernelGGL((harris_kernel<false>), dim3(NIMG*STRIPS), dim3(256), 0, stream,
                       x, maxslot, att);
    hipLaunchKernelGGL((harris_kernel<true>),  dim3(NIMG*STRIPS), dim3(256), 0, stream,
                       x, maxslot, att);
    hipLaunchKernelGGL(conv_kernel, dim3(BATCH*HH), dim3(256), 0, stream,
                       x, wgt, bias, att, out);
}

// Round 3
// 439.423 us; speedup vs baseline: 1.1162x; 1.1162x over previous
//
#include <hip/hip_runtime.h>

#define HH 256
#define WW 256
#define BATCH 8
#define CH 64
#define NIMG (BATCH*CH)      // 512
#define HWSZ (HH*WW)         // 65536
#define SCL (1.0f/12.0f)
#define KH 0.04f
#define TFRAC 0.7f
#define RS 16                // rows per thread-tile in K1
#define NEGINF (-__builtin_inff())

// order-preserving float->uint encoding for atomicMax
__device__ __forceinline__ unsigned encf(float f) {
    unsigned u = __float_as_uint(f);
    return (u & 0x80000000u) ? ~u : (u | 0x80000000u);
}
__device__ __forceinline__ float decf(unsigned u) {
    return __uint_as_float((u & 0x80000000u) ? (u & 0x7fffffffu) : ~u);
}

__global__ void init_kernel(unsigned* ms) {
    int i = blockIdx.x * 256 + threadIdx.x;
    if (i < NIMG) ms[i] = 0u;   // below enc of any real float
}

// K1: register-rolling Harris. Thread = 4 cols x RS rows tile. No LDS (except
// 16B for the block max). Writes vertically-dilated R (Rv) into `rv` (=d_out)
// and per-image max R via atomicMax.
__global__ __launch_bounds__(256) void k1(const float* __restrict__ x,
                                          float* __restrict__ rv,
                                          unsigned* __restrict__ ms)
{
    const int tid = threadIdx.x;
    const int img = blockIdx.x >> 2;                     // 4 blocks per image
    const int tx  = tid & 63;                            // col chunk (4 cols)
    const int sy  = ((blockIdx.x & 3) << 2) | (tid >> 6);// row slab 0..15 (wave-uniform)
    const int r0  = sy * RS;
    const int c0  = tx * 4;
    const float* ib = x + (size_t)img * HWSZ;
    float* rb = rv + (size_t)img * HWSZ;

    float im[3][8];                        // img rows, cols c0-2..c0+5
    float px[3][6], pq[3][6], py[3][6];    // products xx,xy,yy, cols c0-1..c0+4
    float R[3][4];                         // R rows window, cols c0..c0+3
    float rmax = NEGINF;

    auto loadrow = [&](int gr, float* d) {
        gr = gr < 0 ? -gr : (gr >= HH ? 2*HH - 2 - gr : gr);   // reflect101
        const float* rp = ib + gr * WW;
        float4 own = *(const float4*)(rp + c0);
        float4 lf  = (tx > 0)  ? *(const float4*)(rp + c0 - 4) : own;
        float4 rt  = (tx < 63) ? *(const float4*)(rp + c0 + 4) : own;
        d[0] = (tx > 0)  ? lf.z : own.z;   // col -2 -> reflect 2
        d[1] = (tx > 0)  ? lf.w : own.y;   // col -1 -> reflect 1
        d[2] = own.x; d[3] = own.y; d[4] = own.z; d[5] = own.w;
        d[6] = (tx < 63) ? rt.x : own.z;   // col 256 -> reflect 254
        d[7] = (tx < 63) ? rt.y : own.y;   // col 257 -> reflect 253
    };

    loadrow(r0 - 3, im[0]);
    loadrow(r0 - 2, im[1]);

#pragma unroll
    for (int i = 0; i < RS + 4; ++i) {
        const int m = r0 - 2 + i;          // product-row index this step
        loadrow(m + 1, im[(2 + i) % 3]);

        // products row m from img rows m-1,m,m+1 (slots i%3,(i+1)%3,(i+2)%3)
        {
            const int ia = i % 3, ib2 = (i + 1) % 3, ic = (i + 2) % 3;
            float t1[8], t2[8];
#pragma unroll
            for (int q = 0; q < 8; ++q) {
                t1[q] = im[ia][q] + 2.0f * im[ib2][q] + im[ic][q];
                t2[q] = im[ic][q] - im[ia][q];
            }
            const int po = i % 3;
#pragma unroll
            for (int q = 0; q < 6; ++q) {
                float dx = SCL * (t1[q + 2] - t1[q]);
                float dy = SCL * (t2[q] + 2.0f * t2[q + 1] + t2[q + 2]);
                px[po][q] = dx * dx;
                pq[po][q] = dx * dy;
                py[po][q] = dy * dy;
            }
            // Box stage reflects the product FIELD: pxy(-1) = +pxy(1), but
            // recomputing from the reflected image gives -pxy(1) (dx odd, dy
            // even under column reflection). pxx/pyy are even -> already OK.
            if (tx == 0)  pq[po][0] = -pq[po][0];   // col -1
            if (tx == 63) pq[po][5] = -pq[po][5];   // col 256
        }

        // R row s = m-1 (p rows s-1,s,s+1 at slots (i+1)%3,(i+2)%3,i%3)
        if (i >= 2) {
            const int s = m - 1;
            const int A = (i + 1) % 3, B2 = (i + 2) % 3, C2 = i % 3;
            float Sxx[6], Sxy[6], Syy[6];
            if (s == 0) {            // product-field reflect: S(0)=p0+2*p1
#pragma unroll
                for (int q = 0; q < 6; ++q) {
                    Sxx[q] = px[B2][q] + 2.0f * px[C2][q];
                    Sxy[q] = pq[B2][q] + 2.0f * pq[C2][q];
                    Syy[q] = py[B2][q] + 2.0f * py[C2][q];
                }
            } else if (s == HH - 1) { // S(255)=2*p254+p255
#pragma unroll
                for (int q = 0; q < 6; ++q) {
                    Sxx[q] = 2.0f * px[A][q] + px[B2][q];
                    Sxy[q] = 2.0f * pq[A][q] + pq[B2][q];
                    Syy[q] = 2.0f * py[A][q] + py[B2][q];
                }
            } else {
#pragma unroll
                for (int q = 0; q < 6; ++q) {
                    Sxx[q] = px[A][q] + px[B2][q] + px[C2][q];
                    Sxy[q] = pq[A][q] + pq[B2][q] + pq[C2][q];
                    Syy[q] = py[A][q] + py[B2][q] + py[C2][q];
                }
            }
            const bool vs = (s >= 0) && (s < HH);   // wave-uniform
#pragma unroll
            for (int j = 0; j < 4; ++j) {
                float ixx = Sxx[j] + Sxx[j + 1] + Sxx[j + 2];
                float ixy = Sxy[j] + Sxy[j + 1] + Sxy[j + 2];
                float iyy = Syy[j] + Syy[j + 1] + Syy[j + 2];
                float tr = ixx + iyy;
                float Rj = (ixx * iyy - ixy * ixy) - KH * tr * tr;
                Rj = vs ? Rj : NEGINF;
                R[i % 3][j] = Rj;
                rmax = fmaxf(rmax, Rj);
            }
        }

        // Rv row r = m-2 (R rows r-1,r,r+1 at slots (i+1)%3,(i+2)%3,i%3)
        if (i >= 4) {
            const int r = r0 - 4 + i;       // in [r0, r0+RS-1]
            const int A = (i + 1) % 3, B2 = (i + 2) % 3, C2 = i % 3;
            float4 o;
            o.x = fmaxf(fmaxf(R[A][0], R[B2][0]), R[C2][0]);
            o.y = fmaxf(fmaxf(R[A][1], R[B2][1]), R[C2][1]);
            o.z = fmaxf(fmaxf(R[A][2], R[B2][2]), R[C2][2]);
            o.w = fmaxf(fmaxf(R[A][3], R[B2][3]), R[C2][3]);
            *(float4*)(rb + r * WW + c0) = o;
        }
    }

    // per-image max (block spans exactly one image)
#pragma unroll
    for (int off = 32; off; off >>= 1) rmax = fmaxf(rmax, __shfl_xor(rmax, off));
    __shared__ float sm[4];
    if ((tid & 63) == 0) sm[tid >> 6] = rmax;
    __syncthreads();
    if (tid == 0) {
        float mm = fmaxf(fmaxf(sm[0], sm[1]), fmaxf(sm[2], sm[3]));
        atomicMax(ms + img, encf(mm));
    }
}

// K2: per (b,h) row. Horizontal dilate of Rv + threshold + conv1x1 + combine.
// Reads Rv from `io` and overwrites the same addresses with the final output
// (same thread, load-before-store; no cross-block sharing of row h).
__global__ __launch_bounds__(256) void k2(const float* __restrict__ x,
                                          const float* __restrict__ wgt,
                                          const float* __restrict__ bias,
                                          const unsigned* __restrict__ ms,
                                          float* __restrict__ io)
{
    __shared__ float lds[8][WW + 2];
    const int w = threadIdx.x;
    const int b = blockIdx.x >> 8;
    const int h = blockIdx.x & 255;
    const size_t pbase = (size_t)b * CH * HWSZ + (size_t)h * WW + w;

    float xv[CH];
#pragma unroll
    for (int ci = 0; ci < CH; ++ci) xv[ci] = x[pbase + (size_t)ci * HWSZ];

#pragma unroll 1
    for (int g = 0; g < 8; ++g) {
        float rvv[8];
#pragma unroll
        for (int j = 0; j < 8; ++j)
            rvv[j] = io[pbase + (size_t)(g * 8 + j) * HWSZ];
#pragma unroll
        for (int j = 0; j < 8; ++j) {
            lds[j][w + 1] = rvv[j];
            if (w == 0) { lds[j][0] = NEGINF; lds[j][WW + 1] = NEGINF; }
        }
        __syncthreads();
#pragma unroll
        for (int j = 0; j < 8; ++j) {
            const int c = g * 8 + j;
            float dst = fmaxf(fmaxf(lds[j][w], lds[j][w + 1]), lds[j][w + 2]);
            float t = TFRAC * decf(ms[b * CH + c]);
            float acc = bias[c];
            const float* wr = wgt + c * CH;
#pragma unroll
            for (int ci = 0; ci < CH; ++ci) acc = fmaf(wr[ci], xv[ci], acc);
            float y = fmaxf(acc, 0.0f);
            float av = dst > t ? 1.0f : (dst < t ? 0.0f : xv[c]);
            io[pbase + (size_t)c * HWSZ] = fmaf(av, y, xv[c]);
        }
        __syncthreads();
    }
}

extern "C" void kernel_launch(void* const* d_in, const int* in_sizes, int n_in,
                              void* d_out, int out_size, void* d_ws, size_t ws_size,
                              hipStream_t stream)
{
    const float* x    = (const float*)d_in[0];
    const float* wgt  = (const float*)d_in[1];
    const float* bias = (const float*)d_in[2];
    float* out = (float*)d_out;
    unsigned* ms = (unsigned*)d_ws;

    hipLaunchKernelGGL(init_kernel, dim3(2), dim3(256), 0, stream, ms);
    hipLaunchKernelGGL(k1, dim3(NIMG * 4), dim3(256), 0, stream, x, out, ms);
    hipLaunchKernelGGL(k2, dim3(BATCH * HH), dim3(256), 0, stream,
                       x, wgt, bias, ms, out);
}